// Round 3
// baseline (699.943 us; speedup 1.0000x reference)
//
#include <hip/hip_runtime.h>
#include <hip/hip_bf16.h>

#define BB 8
#define NN 1024
#define IN_DIM 256
#define OUT_DIM 256
#define NH 4
#define HD 64

// ---------------- Kernel 1: Wh = h @ W (per head), si = Wh.a1, sj = Wh.a2 ----------------
// grid = B*N blocks, 256 threads. thread t: head hh = t>>6, dim d = t&63.
__global__ __launch_bounds__(256) void wh_kernel(
    const float* __restrict__ h,
    const float* __restrict__ W,
    const float* __restrict__ a1,
    const float* __restrict__ a2,
    float* __restrict__ Wh, float* __restrict__ si, float* __restrict__ sj)
{
    int bn = blockIdx.x;            // b*N + n
    int b = bn >> 10, n = bn & 1023;
    int t = threadIdx.x;
    int hh = t >> 6, d = t & 63;

    __shared__ float hrow[IN_DIM];
    hrow[t] = h[(size_t)bn * IN_DIM + t];
    __syncthreads();

    const float* Wp = W + (size_t)hh * IN_DIM * HD + d;
    float acc = 0.f;
    #pragma unroll 8
    for (int i = 0; i < IN_DIM; ++i) acc += hrow[i] * Wp[(size_t)i * HD];

    int bh = b * NH + hh;
    Wh[((size_t)bh * NN + n) * HD + d] = acc;

    float v1 = acc * a1[hh * HD + d];
    float v2 = acc * a2[hh * HD + d];
    #pragma unroll
    for (int off = 32; off; off >>= 1) {
        v1 += __shfl_xor(v1, off, 64);
        v2 += __shfl_xor(v2, off, 64);
    }
    if (d == 0) { si[(size_t)bh * NN + n] = v1; sj[(size_t)bh * NN + n] = v2; }
}

// ---------------- Kernel 2: masked softmax + alpha @ Wh ----------------
// grid = B*H*N blocks, 256 threads.
__global__ __launch_bounds__(256) void attn_kernel(
    const int* __restrict__ adj,
    const float* __restrict__ Wh,
    const float* __restrict__ si,
    const float* __restrict__ sj,
    float* __restrict__ hm)   // [B,N,OUT_DIM] concat-head layout
{
    int bx = blockIdx.x;            // bh*N + n
    int n = bx & 1023, bh = bx >> 10;
    int t = threadIdx.x;

    __shared__ float p[NN];
    __shared__ float red[4];
    __shared__ float acc4[4][HD];

    float sii = si[(size_t)bh * NN + n];
    const float* sjr = sj + (size_t)bh * NN;
    const int* adjr = adj + (size_t)n * NN;

    float e[4];
    float lmax = -1e30f;
    #pragma unroll
    for (int k = 0; k < 4; ++k) {
        int m = t + k * 256;
        float x = sii + sjr[m];
        x = x > 0.f ? x : 0.2f * x;              // leaky_relu 0.2
        if (adjr[m] == 0) x = -1e9f;             // mask
        e[k] = x;
        lmax = fmaxf(lmax, x);
    }
    #pragma unroll
    for (int off = 32; off; off >>= 1) lmax = fmaxf(lmax, __shfl_xor(lmax, off, 64));
    if ((t & 63) == 0) red[t >> 6] = lmax;
    __syncthreads();
    float gmax = fmaxf(fmaxf(red[0], red[1]), fmaxf(red[2], red[3]));
    __syncthreads();   // red about to be reused

    float lsum = 0.f;
    #pragma unroll
    for (int k = 0; k < 4; ++k) {
        float pv = __expf(e[k] - gmax);
        p[t + k * 256] = pv;
        lsum += pv;
    }
    #pragma unroll
    for (int off = 32; off; off >>= 1) lsum += __shfl_xor(lsum, off, 64);
    if ((t & 63) == 0) red[t >> 6] = lsum;
    __syncthreads();
    float gsum = red[0] + red[1] + red[2] + red[3];

    // weighted sum: out[d] = sum_m p[m] * Wh[m,d]
    int q = t >> 6, d = t & 63;
    const float* Whb = Wh + (size_t)bh * NN * HD;
    float partial = 0.f;
    int m0 = q * 256;
    #pragma unroll 4
    for (int mm = 0; mm < 256; ++mm) {
        partial += p[m0 + mm] * Whb[(size_t)(m0 + mm) * HD + d];
    }
    acc4[q][d] = partial;
    __syncthreads();
    if (q == 0) {
        float o = (acc4[0][d] + acc4[1][d] + acc4[2][d] + acc4[3][d]) / gsum;
        int b = bh >> 2, hh = bh & 3;
        hm[((size_t)(b * NN + n)) * OUT_DIM + hh * HD + d] = o;
    }
}

// ---------------- Kernel 3: projection + bias + residual + LayerNorm ----------------
// grid = B*N blocks, 256 threads (thread = output channel o).
__global__ __launch_bounds__(256) void proj_ln_kernel(
    const float* __restrict__ hm,
    const float* __restrict__ h,
    const float* __restrict__ proj_w,
    const float* __restrict__ proj_b,
    const float* __restrict__ gamma,
    const float* __restrict__ beta,
    float* __restrict__ out)
{
    int bn = blockIdx.x;
    int o = threadIdx.x;

    __shared__ float row[OUT_DIM];
    __shared__ float red[4];
    row[o] = hm[(size_t)bn * OUT_DIM + o];
    __syncthreads();

    const float* wp = proj_w + (size_t)o * OUT_DIM;
    float acc = proj_b[o] + h[(size_t)bn * OUT_DIM + o];
    #pragma unroll 8
    for (int d2 = 0; d2 < OUT_DIM; ++d2) acc += row[d2] * wp[d2];

    // mean
    float v = acc;
    #pragma unroll
    for (int off = 32; off; off >>= 1) v += __shfl_xor(v, off, 64);
    if ((o & 63) == 0) red[o >> 6] = v;
    __syncthreads();
    float mu = (red[0] + red[1] + red[2] + red[3]) * (1.0f / OUT_DIM);
    __syncthreads();

    float c = acc - mu;
    float v2 = c * c;
    #pragma unroll
    for (int off = 32; off; off >>= 1) v2 += __shfl_xor(v2, off, 64);
    if ((o & 63) == 0) red[o >> 6] = v2;
    __syncthreads();
    float var = (red[0] + red[1] + red[2] + red[3]) * (1.0f / OUT_DIM);

    float r = rsqrtf(var + 1e-5f);
    float y = c * r * gamma[o] + beta[o];
    out[(size_t)bn * OUT_DIM + o] = y;
}

extern "C" void kernel_launch(void* const* d_in, const int* in_sizes, int n_in,
                              void* d_out, int out_size, void* d_ws, size_t ws_size,
                              hipStream_t stream) {
    const float* h      = (const float*)d_in[0];
    const int*   adj    = (const int*)d_in[1];
    const float* W      = (const float*)d_in[2];
    const float* a1     = (const float*)d_in[3];
    const float* a2     = (const float*)d_in[4];
    const float* proj_w = (const float*)d_in[5];
    const float* proj_b = (const float*)d_in[6];
    const float* gamma  = (const float*)d_in[7];
    const float* beta   = (const float*)d_in[8];
    float* out = (float*)d_out;

    float* ws = (float*)d_ws;
    float* Wh = ws;                                  // B*H*N*HD    = 2,097,152 floats
    float* si = Wh + (size_t)BB * NH * NN * HD;      // B*H*N       =    32,768
    float* sj = si + (size_t)BB * NH * NN;           // B*H*N
    float* hm = sj + (size_t)BB * NH * NN;           // B*N*OUT_DIM = 2,097,152

    wh_kernel<<<BB * NN, 256, 0, stream>>>(h, W, a1, a2, Wh, si, sj);
    attn_kernel<<<BB * NH * NN, 256, 0, stream>>>(adj, Wh, si, sj, hm);
    proj_ln_kernel<<<BB * NN, 256, 0, stream>>>(hm, h, proj_w, proj_b, gamma, beta, out);
}

// Round 4
// 442.304 us; speedup vs baseline: 1.5825x; 1.5825x over previous
//
#include <hip/hip_runtime.h>
#include <hip/hip_bf16.h>

#define BB 8
#define NN 1024
#define IN_DIM 256
#define OUT_DIM 256
#define NH 4
#define HD 64
#define TN 16            // query rows per attn block
#define PSTRIDE 1032     // p_lds row stride in bf16 elems (1024 + 8 pad, keeps 16B align)

typedef __attribute__((ext_vector_type(8))) short short8;     // 8 x bf16 MFMA frag
typedef __attribute__((ext_vector_type(4))) short short4e;    // 4 x bf16 packed store
typedef __attribute__((ext_vector_type(4))) float floatx4;
typedef __attribute__((ext_vector_type(4))) int intx4;

// ---------------- Kernel 1: WhT(bf16) = (h @ W)^T per head; si = Wh.a1, sj = Wh.a2 ----------------
// grid = B*N blocks, 256 threads. thread t: head hh = t>>6, dim d = t&63.
__global__ __launch_bounds__(256) void wh_kernel(
    const float* __restrict__ h,
    const float* __restrict__ W,
    const float* __restrict__ a1,
    const float* __restrict__ a2,
    __hip_bfloat16* __restrict__ WhT,   // [B*H][HD][NN] bf16
    float* __restrict__ si, float* __restrict__ sj)
{
    int bn = blockIdx.x;            // b*N + n
    int b = bn >> 10, n = bn & 1023;
    int t = threadIdx.x;
    int hh = t >> 6, d = t & 63;

    __shared__ float hrow[IN_DIM];
    hrow[t] = h[(size_t)bn * IN_DIM + t];
    __syncthreads();

    const float* Wp = W + (size_t)hh * IN_DIM * HD + d;
    float acc = 0.f;
    #pragma unroll 8
    for (int i = 0; i < IN_DIM; ++i) acc += hrow[i] * Wp[(size_t)i * HD];

    int bh = b * NH + hh;
    WhT[((size_t)bh * HD + d) * NN + n] = __float2bfloat16(acc);

    float v1 = acc * a1[hh * HD + d];
    float v2 = acc * a2[hh * HD + d];
    #pragma unroll
    for (int off = 32; off; off >>= 1) {
        v1 += __shfl_xor(v1, off, 64);
        v2 += __shfl_xor(v2, off, 64);
    }
    if (d == 0) { si[(size_t)bh * NN + n] = v1; sj[(size_t)bh * NN + n] = v2; }
}

// ---------------- Kernel 2: 16-row tiles: masked softmax (f32) + MFMA alpha @ Wh (bf16) ----------------
// grid = B*H*(N/16) = 2048 blocks, 256 threads.
__global__ __launch_bounds__(256) void attn_kernel(
    const int* __restrict__ adj,
    const __hip_bfloat16* __restrict__ WhT,
    const float* __restrict__ si,
    const float* __restrict__ sj,
    float* __restrict__ hm)   // [B,N,OUT_DIM] concat-head layout
{
    int bx = blockIdx.x;
    int bh = bx >> 6;               // 64 tiles per (b,h)
    int n0 = (bx & 63) * TN;
    int t = threadIdx.x;

    __shared__ __align__(16) __hip_bfloat16 p_lds[TN * PSTRIDE];
    __shared__ float rinv[TN];

    // ---- scores + exp (no max-subtract: |scores| are O(3); masked = -1e9 -> exp = 0) ----
    int r = t >> 4;                 // query row 0..15
    int c = t & 15;                 // column group (interleaved: m = jj*64 + c*4)
    int n = n0 + r;
    float sii = si[(size_t)bh * NN + n];
    const float* sjr = sj + (size_t)bh * NN;
    const int* adjr = adj + (size_t)n * NN;

    float lsum = 0.f;
    #pragma unroll 4
    for (int jj = 0; jj < 16; ++jj) {
        int m = jj * 64 + c * 4;
        floatx4 s4 = *(const floatx4*)(sjr + m);
        intx4 a4 = *(const intx4*)(adjr + m);
        alignas(8) __hip_bfloat16 tmp[4];
        #pragma unroll
        for (int k = 0; k < 4; ++k) {
            float x = sii + s4[k];
            x = x > 0.f ? x : 0.2f * x;          // leaky_relu 0.2
            x = (a4[k] == 0) ? -1e9f : x;        // mask after leaky_relu
            float pv = __expf(x);
            lsum += pv;
            tmp[k] = __float2bfloat16(pv);
        }
        *(short4e*)(p_lds + (size_t)r * PSTRIDE + m) = *(const short4e*)tmp;
    }
    // row-sum over the 16 lanes sharing r (they are contiguous lanes within one wave)
    #pragma unroll
    for (int off = 1; off < 16; off <<= 1) lsum += __shfl_xor(lsum, off, 64);
    if (c == 0) rinv[r] = 1.f / lsum;
    __syncthreads();

    // ---- MFMA: out[16 x 64] = p[16 x 1024] @ Wh[1024 x 64], one 16-wide d-chunk per wave ----
    int w = t >> 6;                 // wave id -> d-chunk
    int l = t & 63;
    int rl = l & 15, q = l >> 4;
    int d0 = w * 16;
    const __hip_bfloat16* Bbase = WhT + ((size_t)bh * HD + d0 + rl) * NN + q * 8;
    const __hip_bfloat16* Abase = p_lds + (size_t)rl * PSTRIDE + q * 8;

    floatx4 acc = {0.f, 0.f, 0.f, 0.f};
    #pragma unroll 4
    for (int k0 = 0; k0 < NN; k0 += 32) {
        short8 af = *(const short8*)(Abase + k0);   // A[m=lane&15][k=(lane>>4)*8+j]
        short8 bf = *(const short8*)(Bbase + k0);   // B[k=(lane>>4)*8+j][n=lane&15]
        acc = __builtin_amdgcn_mfma_f32_16x16x32_bf16(af, bf, acc, 0, 0, 0);
    }

    int b = bh >> 2, hhh = bh & 3;
    #pragma unroll
    for (int i = 0; i < 4; ++i) {
        int nr = q * 4 + i;                         // C row = (lane>>4)*4 + reg
        float v = acc[i] * rinv[nr];
        hm[((size_t)(b * NN) + n0 + nr) * OUT_DIM + hhh * HD + d0 + rl] = v;
    }
}

// ---------------- Kernel 3: projection + bias + residual + LayerNorm ----------------
// grid = B*N blocks, 256 threads (thread = output channel o).
__global__ __launch_bounds__(256) void proj_ln_kernel(
    const float* __restrict__ hm,
    const float* __restrict__ h,
    const float* __restrict__ proj_w,
    const float* __restrict__ proj_b,
    const float* __restrict__ gamma,
    const float* __restrict__ beta,
    float* __restrict__ out)
{
    int bn = blockIdx.x;
    int o = threadIdx.x;

    __shared__ float row[OUT_DIM];
    __shared__ float red[4];
    row[o] = hm[(size_t)bn * OUT_DIM + o];
    __syncthreads();

    const float* wp = proj_w + (size_t)o * OUT_DIM;
    float acc = proj_b[o] + h[(size_t)bn * OUT_DIM + o];
    #pragma unroll 8
    for (int d2 = 0; d2 < OUT_DIM; ++d2) acc += row[d2] * wp[d2];

    float v = acc;
    #pragma unroll
    for (int off = 32; off; off >>= 1) v += __shfl_xor(v, off, 64);
    if ((o & 63) == 0) red[o >> 6] = v;
    __syncthreads();
    float mu = (red[0] + red[1] + red[2] + red[3]) * (1.0f / OUT_DIM);
    __syncthreads();

    float cv = acc - mu;
    float v2 = cv * cv;
    #pragma unroll
    for (int off = 32; off; off >>= 1) v2 += __shfl_xor(v2, off, 64);
    if ((o & 63) == 0) red[o >> 6] = v2;
    __syncthreads();
    float var = (red[0] + red[1] + red[2] + red[3]) * (1.0f / OUT_DIM);

    float rr = rsqrtf(var + 1e-5f);
    float y = cv * rr * gamma[o] + beta[o];
    out[(size_t)bn * OUT_DIM + o] = y;
}

extern "C" void kernel_launch(void* const* d_in, const int* in_sizes, int n_in,
                              void* d_out, int out_size, void* d_ws, size_t ws_size,
                              hipStream_t stream) {
    const float* h      = (const float*)d_in[0];
    const int*   adj    = (const int*)d_in[1];
    const float* W      = (const float*)d_in[2];
    const float* a1     = (const float*)d_in[3];
    const float* a2     = (const float*)d_in[4];
    const float* proj_w = (const float*)d_in[5];
    const float* proj_b = (const float*)d_in[6];
    const float* gamma  = (const float*)d_in[7];
    const float* beta   = (const float*)d_in[8];
    float* out = (float*)d_out;

    // workspace: WhT bf16 [32][64][1024] = 4 MB, then f32 arrays
    __hip_bfloat16* WhT = (__hip_bfloat16*)d_ws;
    float* si = (float*)((char*)d_ws + (size_t)BB * NH * NN * HD * sizeof(__hip_bfloat16));
    float* sj = si + (size_t)BB * NH * NN;
    float* hm = sj + (size_t)BB * NH * NN;           // B*N*OUT_DIM floats

    wh_kernel<<<BB * NN, 256, 0, stream>>>(h, W, a1, a2, WhT, si, sj);
    attn_kernel<<<BB * NH * (NN / TN), 256, 0, stream>>>(adj, WhT, si, sj, hm);
    proj_ln_kernel<<<BB * NN, 256, 0, stream>>>(hm, h, proj_w, proj_b, gamma, beta, out);
}

// Round 5
// 195.644 us; speedup vs baseline: 3.5776x; 2.2608x over previous
//
#include <hip/hip_runtime.h>
#include <hip/hip_bf16.h>

#define BB 8
#define NN 1024
#define IN_DIM 256
#define OUT_DIM 256
#define NH 4
#define HD 64
#define TN 16            // query rows per attn block
#define PSTRIDE 1032     // p_lds row stride in bf16 elems (1024 + 8 pad)

typedef __attribute__((ext_vector_type(8))) short short8;     // 8 x bf16 MFMA frag
typedef __attribute__((ext_vector_type(4))) short short4e;    // 4 x bf16 packed store
typedef __attribute__((ext_vector_type(4))) float floatx4;
typedef __attribute__((ext_vector_type(4))) int intx4;

// ---------------- Kernel 0: prep — bf16 casts / transposes / folded score vectors ----------------
// grid = 2048 (h cast) + 16 (W transpose) + 16 (proj_w cast) + 1 (wab) = 2081 blocks, 256 threads
__global__ __launch_bounds__(256) void prep_kernel(
    const float* __restrict__ h, const float* __restrict__ W,
    const float* __restrict__ a1, const float* __restrict__ a2,
    const float* __restrict__ proj_w,
    __hip_bfloat16* __restrict__ hb,      // [8192][256]
    __hip_bfloat16* __restrict__ WTb,     // [256 o][256 k], o = hh*64+d
    __hip_bfloat16* __restrict__ pwb,     // [256 o][256 k] (= proj_w layout)
    __hip_bfloat16* __restrict__ wab)     // [16][256]: rows 0-3 W@a1 per head, 4-7 W@a2, 8-15 zero
{
    int blk = blockIdx.x, t = threadIdx.x;
    if (blk < 2048) {
        size_t base = (size_t)blk * 1024 + t * 4;
        floatx4 v = *(const floatx4*)(h + base);
        alignas(8) __hip_bfloat16 tmp[4];
        #pragma unroll
        for (int k = 0; k < 4; ++k) tmp[k] = __float2bfloat16(v[k]);
        *(short4e*)(hb + base) = *(const short4e*)tmp;
    } else if (blk < 2064) {
        int o = (blk - 2048) * 16 + (t >> 4);
        int hh = o >> 6, d = o & 63;
        #pragma unroll
        for (int kk = 0; kk < 16; ++kk) {
            int k = (t & 15) + 16 * kk;
            WTb[(size_t)o * 256 + k] = __float2bfloat16(W[((size_t)hh * 256 + k) * 64 + d]);
        }
    } else if (blk < 2080) {
        size_t base = (size_t)(blk - 2064) * 4096 + t * 16;
        #pragma unroll
        for (int k = 0; k < 16; k += 4) {
            floatx4 v = *(const floatx4*)(proj_w + base + k);
            alignas(8) __hip_bfloat16 tmp[4];
            #pragma unroll
            for (int j = 0; j < 4; ++j) tmp[j] = __float2bfloat16(v[j]);
            *(short4e*)(pwb + base + k) = *(const short4e*)tmp;
        }
    } else {
        for (int e = t; e < 4096; e += 256) {
            int r = e >> 8, k = e & 255;
            float s = 0.f;
            if (r < 8) {
                int hh = r & 3;
                const float* av = (r < 4 ? a1 : a2) + hh * HD;
                const float* wrow = W + ((size_t)hh * 256 + k) * HD;
                #pragma unroll 8
                for (int d = 0; d < HD; ++d) s += wrow[d] * av[d];
            }
            wab[(size_t)r * 256 + k] = __float2bfloat16(s);
        }
    }
}

// ---------------- Kernel 1: Wh via MFMA; si/sj as extra GEMM columns ----------------
// grid = 8192/64 = 128 blocks, 256 threads = 4 waves; wave w handles rows r0..r0+15.
__global__ __launch_bounds__(256) void wh_mfma_kernel(
    const __hip_bfloat16* __restrict__ hb,
    const __hip_bfloat16* __restrict__ WTb,
    const __hip_bfloat16* __restrict__ wab,
    __hip_bfloat16* __restrict__ WhT,    // [B*H][HD][NN]
    float* __restrict__ si, float* __restrict__ sj)
{
    int t = threadIdx.x;
    int w = t >> 6, l = t & 63;
    int rl = l & 15, q = l >> 4;
    int r0 = blockIdx.x * 64 + w * 16;

    // A-frags: A[m=lane&15][k=(lane>>4)*8+j] = hb[r0+rl][...]
    short8 af[8];
    const __hip_bfloat16* Arow = hb + (size_t)(r0 + rl) * 256 + q * 8;
    #pragma unroll
    for (int k0 = 0; k0 < 8; ++k0) af[k0] = *(const short8*)(Arow + k0 * 32);

    floatx4 acc[16];
    #pragma unroll
    for (int ct = 0; ct < 16; ++ct) acc[ct] = (floatx4){0.f, 0.f, 0.f, 0.f};
    floatx4 acce = {0.f, 0.f, 0.f, 0.f};

    #pragma unroll
    for (int ct = 0; ct < 16; ++ct) {
        const __hip_bfloat16* Brow = WTb + (size_t)(ct * 16 + rl) * 256 + q * 8;
        #pragma unroll
        for (int k0 = 0; k0 < 8; ++k0) {
            short8 bf = *(const short8*)(Brow + k0 * 32);   // B[k][n=lane&15] from [n][k] store
            acc[ct] = __builtin_amdgcn_mfma_f32_16x16x32_bf16(af[k0], bf, acc[ct], 0, 0, 0);
        }
    }
    {
        const __hip_bfloat16* Brow = wab + (size_t)rl * 256 + q * 8;
        #pragma unroll
        for (int k0 = 0; k0 < 8; ++k0) {
            short8 bf = *(const short8*)(Brow + k0 * 32);
            acce = __builtin_amdgcn_mfma_f32_16x16x32_bf16(af[k0], bf, acce, 0, 0, 0);
        }
    }

    // C layout: col = lane&15 (=rl), row = (lane>>4)*4 + i
    int bb = r0 >> 10;
    int nbase = (r0 & 1023) + q * 4;
    #pragma unroll
    for (int ct = 0; ct < 16; ++ct) {
        int hh = ct >> 2, d = (ct & 3) * 16 + rl;
        int bh = bb * NH + hh;
        alignas(8) __hip_bfloat16 tmp[4];
        #pragma unroll
        for (int i = 0; i < 4; ++i) tmp[i] = __float2bfloat16(acc[ct][i]);
        *(short4e*)(WhT + ((size_t)bh * HD + d) * NN + nbase) = *(const short4e*)tmp;
    }
    if (rl < 8) {
        int hh = rl & 3;
        float* dst = (rl < 4 ? si : sj) + ((size_t)(bb * NH + hh)) * NN + nbase;
        #pragma unroll
        for (int i = 0; i < 4; ++i) dst[i] = acce[i];
    }
}

// ---------------- Kernel 2: 16-row tiles: masked softmax (f32) + MFMA alpha @ Wh ----------------
// grid = B*H*(N/16) = 2048 blocks, 256 threads.
__global__ __launch_bounds__(256) void attn_kernel(
    const int* __restrict__ adj,
    const __hip_bfloat16* __restrict__ WhT,
    const float* __restrict__ si,
    const float* __restrict__ sj,
    __hip_bfloat16* __restrict__ hmb)   // [B*N][OUT_DIM] bf16, concat-head layout
{
    int bx = blockIdx.x;
    int bh = bx >> 6;
    int n0 = (bx & 63) * TN;
    int t = threadIdx.x;

    __shared__ __align__(16) __hip_bfloat16 p_lds[TN * PSTRIDE];
    __shared__ float rinv[TN];

    int r = t >> 4;
    int c = t & 15;
    int n = n0 + r;
    float sii = si[(size_t)bh * NN + n];
    const float* sjr = sj + (size_t)bh * NN;
    const int* adjr = adj + (size_t)n * NN;

    float lsum = 0.f;
    #pragma unroll 4
    for (int jj = 0; jj < 16; ++jj) {
        int m = jj * 64 + c * 4;
        floatx4 s4 = *(const floatx4*)(sjr + m);
        intx4 a4 = *(const intx4*)(adjr + m);
        alignas(8) __hip_bfloat16 tmp[4];
        #pragma unroll
        for (int k = 0; k < 4; ++k) {
            float x = sii + s4[k];
            x = x > 0.f ? x : 0.2f * x;
            x = (a4[k] == 0) ? -1e9f : x;
            float pv = __expf(x);
            lsum += pv;
            tmp[k] = __float2bfloat16(pv);
        }
        *(short4e*)(p_lds + (size_t)r * PSTRIDE + m) = *(const short4e*)tmp;
    }
    #pragma unroll
    for (int off = 1; off < 16; off <<= 1) lsum += __shfl_xor(lsum, off, 64);
    if (c == 0) rinv[r] = 1.f / lsum;
    __syncthreads();

    int w = t >> 6;
    int l = t & 63;
    int rl = l & 15, q = l >> 4;
    int d0 = w * 16;
    const __hip_bfloat16* Bbase = WhT + ((size_t)bh * HD + d0 + rl) * NN + q * 8;
    const __hip_bfloat16* Abase = p_lds + (size_t)rl * PSTRIDE + q * 8;

    floatx4 acc = {0.f, 0.f, 0.f, 0.f};
    #pragma unroll 4
    for (int k0 = 0; k0 < NN; k0 += 32) {
        short8 af = *(const short8*)(Abase + k0);
        short8 bf = *(const short8*)(Bbase + k0);
        acc = __builtin_amdgcn_mfma_f32_16x16x32_bf16(af, bf, acc, 0, 0, 0);
    }

    int b = bh >> 2, hhh = bh & 3;
    #pragma unroll
    for (int i = 0; i < 4; ++i) {
        int nr = q * 4 + i;
        float v = acc[i] * rinv[nr];
        hmb[((size_t)(b * NN) + n0 + nr) * OUT_DIM + hhh * HD + d0 + rl] = __float2bfloat16(v);
    }
}

// ---------------- Kernel 3: proj via MFMA + bias + residual + LayerNorm in registers ----------------
// grid = 128 blocks, 256 threads = 4 waves; wave w: rows r0..r0+15, all 256 cols.
__global__ __launch_bounds__(256) void proj_ln_kernel(
    const __hip_bfloat16* __restrict__ hmb,
    const float* __restrict__ h,
    const __hip_bfloat16* __restrict__ pwb,
    const float* __restrict__ proj_b,
    const float* __restrict__ gamma,
    const float* __restrict__ beta,
    float* __restrict__ out)
{
    int t = threadIdx.x;
    int w = t >> 6, l = t & 63;
    int rl = l & 15, q = l >> 4;
    int r0 = blockIdx.x * 64 + w * 16;

    short8 af[8];
    const __hip_bfloat16* Arow = hmb + (size_t)(r0 + rl) * 256 + q * 8;
    #pragma unroll
    for (int k0 = 0; k0 < 8; ++k0) af[k0] = *(const short8*)(Arow + k0 * 32);

    floatx4 acc[16];
    #pragma unroll
    for (int ct = 0; ct < 16; ++ct) acc[ct] = (floatx4){0.f, 0.f, 0.f, 0.f};

    #pragma unroll
    for (int ct = 0; ct < 16; ++ct) {
        const __hip_bfloat16* Brow = pwb + (size_t)(ct * 16 + rl) * 256 + q * 8;
        #pragma unroll
        for (int k0 = 0; k0 < 8; ++k0) {
            short8 bf = *(const short8*)(Brow + k0 * 32);
            acc[ct] = __builtin_amdgcn_mfma_f32_16x16x32_bf16(af[k0], bf, acc[ct], 0, 0, 0);
        }
    }

    // bias + residual, accumulate row sums (rows r0+q*4+i, cols ct*16+rl)
    float mu[4] = {0.f, 0.f, 0.f, 0.f};
    #pragma unroll
    for (int ct = 0; ct < 16; ++ct) {
        int col = ct * 16 + rl;
        float pb = proj_b[col];
        #pragma unroll
        for (int i = 0; i < 4; ++i) {
            float v = acc[ct][i] + pb + h[(size_t)(r0 + q * 4 + i) * 256 + col];
            acc[ct][i] = v;
            mu[i] += v;
        }
    }
    #pragma unroll
    for (int i = 0; i < 4; ++i) {
        float s = mu[i];
        #pragma unroll
        for (int off = 1; off < 16; off <<= 1) s += __shfl_xor(s, off, 64);
        mu[i] = s * (1.f / 256.f);
    }
    float rs[4] = {0.f, 0.f, 0.f, 0.f};
    #pragma unroll
    for (int ct = 0; ct < 16; ++ct) {
        #pragma unroll
        for (int i = 0; i < 4; ++i) { float cv = acc[ct][i] - mu[i]; rs[i] += cv * cv; }
    }
    #pragma unroll
    for (int i = 0; i < 4; ++i) {
        float s = rs[i];
        #pragma unroll
        for (int off = 1; off < 16; off <<= 1) s += __shfl_xor(s, off, 64);
        rs[i] = rsqrtf(s * (1.f / 256.f) + 1e-5f);
    }
    #pragma unroll
    for (int ct = 0; ct < 16; ++ct) {
        int col = ct * 16 + rl;
        float g = gamma[col], be = beta[col];
        #pragma unroll
        for (int i = 0; i < 4; ++i)
            out[(size_t)(r0 + q * 4 + i) * 256 + col] = (acc[ct][i] - mu[i]) * rs[i] * g + be;
    }
}

extern "C" void kernel_launch(void* const* d_in, const int* in_sizes, int n_in,
                              void* d_out, int out_size, void* d_ws, size_t ws_size,
                              hipStream_t stream) {
    const float* h      = (const float*)d_in[0];
    const int*   adj    = (const int*)d_in[1];
    const float* W      = (const float*)d_in[2];
    const float* a1     = (const float*)d_in[3];
    const float* a2     = (const float*)d_in[4];
    const float* proj_w = (const float*)d_in[5];
    const float* proj_b = (const float*)d_in[6];
    const float* gamma  = (const float*)d_in[7];
    const float* beta   = (const float*)d_in[8];
    float* out = (float*)d_out;

    char* ws = (char*)d_ws;
    __hip_bfloat16* hb  = (__hip_bfloat16*)ws;                    ws += (size_t)BB*NN*IN_DIM*2;   // 4 MB
    __hip_bfloat16* WhT = (__hip_bfloat16*)ws;                    ws += (size_t)BB*NH*HD*NN*2;    // 4 MB
    __hip_bfloat16* hmb = (__hip_bfloat16*)ws;                    ws += (size_t)BB*NN*OUT_DIM*2;  // 4 MB
    __hip_bfloat16* WTb = (__hip_bfloat16*)ws;                    ws += 256*256*2;                // 128 KB
    __hip_bfloat16* pwb = (__hip_bfloat16*)ws;                    ws += 256*256*2;                // 128 KB
    __hip_bfloat16* wab = (__hip_bfloat16*)ws;                    ws += 16*256*2;                 // 8 KB
    float* si = (float*)ws;                                       ws += (size_t)BB*NH*NN*4;       // 128 KB
    float* sj = (float*)ws;

    prep_kernel<<<2081, 256, 0, stream>>>(h, W, a1, a2, proj_w, hb, WTb, pwb, wab);
    wh_mfma_kernel<<<128, 256, 0, stream>>>(hb, WTb, wab, WhT, si, sj);
    attn_kernel<<<BB * NH * (NN / TN), 256, 0, stream>>>(adj, WhT, si, sj, hmb);
    proj_ln_kernel<<<128, 256, 0, stream>>>(hmb, h, pwb, proj_b, gamma, beta, out);
}

// Round 7
// 144.725 us; speedup vs baseline: 4.8363x; 1.3518x over previous
//
#include <hip/hip_runtime.h>
#include <hip/hip_bf16.h>

#define BB 8
#define NN 1024
#define IN_DIM 256
#define OUT_DIM 256
#define NH 4
#define HD 64
#define TN 16            // query rows per attn block
#define PSTRIDE 1032     // p_lds row stride in bf16 elems (1024 + 8 pad)

typedef __attribute__((ext_vector_type(8))) short short8;     // 8 x bf16 MFMA frag
typedef __attribute__((ext_vector_type(4))) short short4e;    // 4 x bf16 packed store
typedef __attribute__((ext_vector_type(4))) float floatx4;
typedef __attribute__((ext_vector_type(4))) int intx4;

// ---------------- Kernel 0: prep — WTb / pwb bf16, wab folded score vectors ----------------
// grid = 16 (W transpose) + 16 (proj_w cast) + 8 (wab rows) = 40 blocks, 256 threads
__global__ __launch_bounds__(256) void prep_kernel(
    const float* __restrict__ W,
    const float* __restrict__ a1, const float* __restrict__ a2,
    const float* __restrict__ proj_w,
    __hip_bfloat16* __restrict__ WTb,     // [256 o][256 k], o = hh*64+d
    __hip_bfloat16* __restrict__ pwb,     // [256 o][256 k] (= proj_w layout)
    __hip_bfloat16* __restrict__ wab)     // [16][256]: rows 0-3 W@a1 per head, 4-7 W@a2, 8-15 zero
{
    int blk = blockIdx.x, t = threadIdx.x;
    if (blk < 16) {
        int o = blk * 16 + (t >> 4);
        int hh = o >> 6, d = o & 63;
        #pragma unroll
        for (int kk = 0; kk < 16; ++kk) {
            int k = (t & 15) + 16 * kk;
            WTb[(size_t)o * 256 + k] = __float2bfloat16(W[((size_t)hh * 256 + k) * 64 + d]);
        }
    } else if (blk < 32) {
        size_t base = (size_t)(blk - 16) * 4096 + t * 16;
        #pragma unroll
        for (int k = 0; k < 16; k += 4) {
            floatx4 v = *(const floatx4*)(proj_w + base + k);
            alignas(8) __hip_bfloat16 tmp[4];
            #pragma unroll
            for (int j = 0; j < 4; ++j) tmp[j] = __float2bfloat16(v[j]);
            *(short4e*)(pwb + base + k) = *(const short4e*)tmp;
        }
    } else {
        int r = blk - 32;                 // 0..7
        int hh = r & 3;
        const float* av = (r < 4 ? a1 : a2) + hh * HD;
        const float* wrow = W + ((size_t)hh * 256 + t) * HD;
        float s = 0.f;
        #pragma unroll 8
        for (int d = 0; d < HD; ++d) s += wrow[d] * av[d];
        wab[(size_t)r * 256 + t] = __float2bfloat16(s);
        wab[(size_t)(r + 8) * 256 + t] = __float2bfloat16(0.f);
    }
}

// ---------------- Kernel 1: Wh via MFMA (f32 h read + inline bf16 cast); si/sj as extra cols ----------------
// grid = 8192/16 = 512 blocks, 256 threads = 4 waves; all waves share 16 rows, wave w takes col-tiles w+4j.
__global__ __launch_bounds__(256) void wh_mfma_kernel(
    const float* __restrict__ h,
    const __hip_bfloat16* __restrict__ WTb,
    const __hip_bfloat16* __restrict__ wab,
    __hip_bfloat16* __restrict__ WhT,    // [B*H][HD][NN]
    float* __restrict__ si, float* __restrict__ sj)
{
    int t = threadIdx.x;
    int w = t >> 6, l = t & 63;
    int rl = l & 15, q = l >> 4;
    int r0 = blockIdx.x * 16;

    // A-frags: A[m=lane&15][k=(lane>>4)*8+j] = h[r0+rl][k], cast f32->bf16 in regs
    short8 af[8];
    const float* Arow = h + (size_t)(r0 + rl) * 256 + q * 8;
    #pragma unroll
    for (int k0 = 0; k0 < 8; ++k0) {
        floatx4 v0 = *(const floatx4*)(Arow + k0 * 32);
        floatx4 v1 = *(const floatx4*)(Arow + k0 * 32 + 4);
        short8 a;
        #pragma unroll
        for (int j = 0; j < 4; ++j) {
            a[j]     = (short)(__bfloat16_as_ushort(__float2bfloat16(v0[j])));
            a[j + 4] = (short)(__bfloat16_as_ushort(__float2bfloat16(v1[j])));
        }
        af[k0] = a;
    }

    int bb = r0 >> 10;
    int n0 = (r0 & 1023) + q * 4;

    #pragma unroll
    for (int j = 0; j < 4; ++j) {
        int ct = w + j * 4;
        const __hip_bfloat16* Brow = WTb + (size_t)(ct * 16 + rl) * 256 + q * 8;
        floatx4 acc = {0.f, 0.f, 0.f, 0.f};
        #pragma unroll
        for (int k0 = 0; k0 < 8; ++k0) {
            short8 bf = *(const short8*)(Brow + k0 * 32);
            acc = __builtin_amdgcn_mfma_f32_16x16x32_bf16(af[k0], bf, acc, 0, 0, 0);
        }
        int o = ct * 16 + rl;
        int hh = o >> 6, d = o & 63;
        alignas(8) __hip_bfloat16 tmp[4];
        #pragma unroll
        for (int i = 0; i < 4; ++i) tmp[i] = __float2bfloat16(acc[i]);
        *(short4e*)(WhT + ((size_t)(bb * NH + hh) * HD + d) * NN + n0) = *(const short4e*)tmp;
    }

    if (w == 0) {   // extra tile: si/sj from wab columns
        const __hip_bfloat16* Brow = wab + (size_t)rl * 256 + q * 8;
        floatx4 acc = {0.f, 0.f, 0.f, 0.f};
        #pragma unroll
        for (int k0 = 0; k0 < 8; ++k0) {
            short8 bf = *(const short8*)(Brow + k0 * 32);
            acc = __builtin_amdgcn_mfma_f32_16x16x32_bf16(af[k0], bf, acc, 0, 0, 0);
        }
        if (rl < 8) {
            int hh = rl & 3;
            float* dst = (rl < 4 ? si : sj) + ((size_t)(bb * NH + hh)) * NN + n0;
            *(floatx4*)dst = acc;
        }
    }
}

// ---------------- Kernel 2: 16-row tiles: masked softmax (f32) + MFMA alpha @ Wh ----------------
// grid = B*H*(N/16) = 2048 blocks, 256 threads.
__global__ __launch_bounds__(256) void attn_kernel(
    const int* __restrict__ adj,
    const __hip_bfloat16* __restrict__ WhT,
    const float* __restrict__ si,
    const float* __restrict__ sj,
    __hip_bfloat16* __restrict__ hmb)   // [B*N][OUT_DIM] bf16, concat-head layout
{
    int bx = blockIdx.x;
    int bh = bx >> 6;
    int n0 = (bx & 63) * TN;
    int t = threadIdx.x;

    __shared__ __align__(16) __hip_bfloat16 p_lds[TN * PSTRIDE];
    __shared__ float rinv[TN];

    int r = t >> 4;
    int c = t & 15;
    int n = n0 + r;
    float sii = si[(size_t)bh * NN + n];
    const float* sjr = sj + (size_t)bh * NN;
    const int* adjr = adj + (size_t)n * NN;

    float lsum = 0.f;
    #pragma unroll 4
    for (int jj = 0; jj < 16; ++jj) {
        int m = jj * 64 + c * 4;
        floatx4 s4 = *(const floatx4*)(sjr + m);
        intx4 a4 = *(const intx4*)(adjr + m);
        alignas(8) __hip_bfloat16 tmp[4];
        #pragma unroll
        for (int k = 0; k < 4; ++k) {
            float x = sii + s4[k];
            x = x > 0.f ? x : 0.2f * x;
            x = (a4[k] == 0) ? -1e9f : x;
            float pv = __expf(x);
            lsum += pv;
            tmp[k] = __float2bfloat16(pv);
        }
        *(short4e*)(p_lds + (size_t)r * PSTRIDE + m) = *(const short4e*)tmp;
    }
    #pragma unroll
    for (int off = 1; off < 16; off <<= 1) lsum += __shfl_xor(lsum, off, 64);
    if (c == 0) rinv[r] = 1.f / lsum;
    __syncthreads();

    int w = t >> 6;
    int l = t & 63;
    int rl = l & 15, q = l >> 4;
    int d0 = w * 16;
    const __hip_bfloat16* Bbase = WhT + ((size_t)bh * HD + d0 + rl) * NN + q * 8;
    const __hip_bfloat16* Abase = p_lds + (size_t)rl * PSTRIDE + q * 8;

    floatx4 acc = {0.f, 0.f, 0.f, 0.f};
    #pragma unroll 4
    for (int k0 = 0; k0 < NN; k0 += 32) {
        short8 af = *(const short8*)(Abase + k0);
        short8 bf = *(const short8*)(Bbase + k0);
        acc = __builtin_amdgcn_mfma_f32_16x16x32_bf16(af, bf, acc, 0, 0, 0);
    }

    int b = bh >> 2, hhh = bh & 3;
    #pragma unroll
    for (int i = 0; i < 4; ++i) {
        int nr = q * 4 + i;
        float v = acc[i] * rinv[nr];
        hmb[((size_t)(b * NN) + n0 + nr) * OUT_DIM + hhh * HD + d0 + rl] = __float2bfloat16(v);
    }
}

// ---------------- Kernel 3: proj via MFMA + bias + residual + LayerNorm (cross-wave LDS reduce) ----------------
// grid = 512 blocks, 256 threads = 4 waves; all waves share 16 rows, wave w takes col-tiles w+4j.
__global__ __launch_bounds__(256) void proj_ln_kernel(
    const __hip_bfloat16* __restrict__ hmb,
    const float* __restrict__ h,
    const __hip_bfloat16* __restrict__ pwb,
    const float* __restrict__ proj_b,
    const float* __restrict__ gamma,
    const float* __restrict__ beta,
    float* __restrict__ out)
{
    int t = threadIdx.x;
    int w = t >> 6, l = t & 63;
    int rl = l & 15, q = l >> 4;
    int r0 = blockIdx.x * 16;

    __shared__ float red[2][4][16];   // [pass][wave][row]

    short8 af[8];
    const __hip_bfloat16* Arow = hmb + (size_t)(r0 + rl) * 256 + q * 8;
    #pragma unroll
    for (int k0 = 0; k0 < 8; ++k0) af[k0] = *(const short8*)(Arow + k0 * 32);

    floatx4 acc[4];
    #pragma unroll
    for (int j = 0; j < 4; ++j) {
        int ct = w + j * 4;
        const __hip_bfloat16* Brow = pwb + (size_t)(ct * 16 + rl) * 256 + q * 8;
        floatx4 a = {0.f, 0.f, 0.f, 0.f};
        #pragma unroll
        for (int k0 = 0; k0 < 8; ++k0) {
            short8 bf = *(const short8*)(Brow + k0 * 32);
            a = __builtin_amdgcn_mfma_f32_16x16x32_bf16(af[k0], bf, a, 0, 0, 0);
        }
        acc[j] = a;
    }

    // bias + residual; per-lane partial row sums over this wave's 16 cols
    float ps[4] = {0.f, 0.f, 0.f, 0.f};
    #pragma unroll
    for (int j = 0; j < 4; ++j) {
        int col = (w + j * 4) * 16 + rl;
        float pb = proj_b[col];
        #pragma unroll
        for (int i = 0; i < 4; ++i) {
            float v = acc[j][i] + pb + h[(size_t)(r0 + q * 4 + i) * 256 + col];
            acc[j][i] = v;
            ps[i] += v;
        }
    }
    #pragma unroll
    for (int i = 0; i < 4; ++i) {
        float s = ps[i];
        #pragma unroll
        for (int off = 1; off < 16; off <<= 1) s += __shfl_xor(s, off, 64);
        ps[i] = s;
    }
    if (rl == 0) {
        for (int i = 0; i < 4; ++i) red[0][w][q * 4 + i] = ps[i];
    }
    __syncthreads();
    float mu[4];
    #pragma unroll
    for (int i = 0; i < 4; ++i) {
        int row = q * 4 + i;
        mu[i] = (red[0][0][row] + red[0][1][row] + red[0][2][row] + red[0][3][row]) * (1.f / 256.f);
    }

    float vs[4] = {0.f, 0.f, 0.f, 0.f};
    #pragma unroll
    for (int j = 0; j < 4; ++j) {
        #pragma unroll
        for (int i = 0; i < 4; ++i) { float cv = acc[j][i] - mu[i]; vs[i] += cv * cv; }
    }
    #pragma unroll
    for (int i = 0; i < 4; ++i) {
        float s = vs[i];
        #pragma unroll
        for (int off = 1; off < 16; off <<= 1) s += __shfl_xor(s, off, 64);
        vs[i] = s;
    }
    if (rl == 0) {
        for (int i = 0; i < 4; ++i) red[1][w][q * 4 + i] = vs[i];
    }
    __syncthreads();
    float rs[4];
    #pragma unroll
    for (int i = 0; i < 4; ++i) {
        int row = q * 4 + i;
        float var = (red[1][0][row] + red[1][1][row] + red[1][2][row] + red[1][3][row]) * (1.f / 256.f);
        rs[i] = rsqrtf(var + 1e-5f);
    }

    #pragma unroll
    for (int j = 0; j < 4; ++j) {
        int col = (w + j * 4) * 16 + rl;
        float g = gamma[col], be = beta[col];
        #pragma unroll
        for (int i = 0; i < 4; ++i)
            out[(size_t)(r0 + q * 4 + i) * 256 + col] = (acc[j][i] - mu[i]) * rs[i] * g + be;
    }
}

extern "C" void kernel_launch(void* const* d_in, const int* in_sizes, int n_in,
                              void* d_out, int out_size, void* d_ws, size_t ws_size,
                              hipStream_t stream) {
    const float* h      = (const float*)d_in[0];
    const int*   adj    = (const int*)d_in[1];
    const float* W      = (const float*)d_in[2];
    const float* a1     = (const float*)d_in[3];
    const float* a2     = (const float*)d_in[4];
    const float* proj_w = (const float*)d_in[5];
    const float* proj_b = (const float*)d_in[6];
    const float* gamma  = (const float*)d_in[7];
    const float* beta   = (const float*)d_in[8];
    float* out = (float*)d_out;

    char* ws = (char*)d_ws;
    __hip_bfloat16* WhT = (__hip_bfloat16*)ws;                    ws += (size_t)BB*NH*HD*NN*2;    // 4 MB
    __hip_bfloat16* hmb = (__hip_bfloat16*)ws;                    ws += (size_t)BB*NN*OUT_DIM*2;  // 4 MB
    __hip_bfloat16* WTb = (__hip_bfloat16*)ws;                    ws += 256*256*2;                // 128 KB
    __hip_bfloat16* pwb = (__hip_bfloat16*)ws;                    ws += 256*256*2;                // 128 KB
    __hip_bfloat16* wab = (__hip_bfloat16*)ws;                    ws += 16*256*2;                 // 8 KB
    float* si = (float*)ws;                                       ws += (size_t)BB*NH*NN*4;       // 128 KB
    float* sj = (float*)ws;

    prep_kernel<<<40, 256, 0, stream>>>(W, a1, a2, proj_w, WTb, pwb, wab);
    wh_mfma_kernel<<<512, 256, 0, stream>>>(h, WTb, wab, WhT, si, sj);
    attn_kernel<<<BB * NH * (NN / TN), 256, 0, stream>>>(adj, WhT, si, sj, hmb);
    proj_ln_kernel<<<512, 256, 0, stream>>>(hmb, h, pwb, proj_b, gamma, beta, out);
}